// Round 1
// baseline (24.413 us; speedup 1.0000x reference)
//
#include <hip/hip_runtime.h>
#include <hip/hip_bf16.h>
#include <math.h>

// Shapes (fixed by the reference):
//   B=2, L=385, C=128, N=L-1=384, 2C=256
// x: (B,L,C) f32 ; gamma,beta: (2C,) ; W: (C,2C) ; b: (C,)
// out: (B,L,C) f32

#define B_  2
#define L_  385
#define C_  128
#define N_  384
#define EPS_ 1e-5f

// ---------------------------------------------------------------------------
// Kernel A: per (b,c) compute
//   V[b,c]   = var_j F[b,j,c]                (population var, ddof=0)
//   s        = gamma[c] / sqrt(V + eps)
//   w_j      = softmax_j(s * F[b,j,c])
//   M        = sum_j w_j * F[b,j,c]
//   ws_a[bc] = s
//   ws_u[bc] = s*M + beta[c]
// One wave (64 lanes) per (b,c). grid = B*C = 256, block = 64.
// ---------------------------------------------------------------------------
__global__ __launch_bounds__(64) void lnp_stats_kernel(
    const float* __restrict__ x, const float* __restrict__ gamma,
    const float* __restrict__ beta, float* __restrict__ ws_a,
    float* __restrict__ ws_u) {
  const int bc = blockIdx.x;
  const int b  = bc >> 7;       // / C_
  const int c  = bc & 127;      // % C_
  const int lane = threadIdx.x;

  const float* Fp = x + (size_t)b * L_ * C_ + C_ + c;  // F[b, j, c] at Fp[j*C_]

  float v[6];
  float s1 = 0.f, s2 = 0.f;
#pragma unroll
  for (int t = 0; t < 6; ++t) {
    const int j = lane + 64 * t;
    const float f = Fp[(size_t)j * C_];
    v[t] = f;
    s1 += f;
    s2 += f * f;
  }
#pragma unroll
  for (int off = 32; off; off >>= 1) {
    s1 += __shfl_xor(s1, off);
    s2 += __shfl_xor(s2, off);
  }
  const float mean = s1 * (1.0f / N_);
  float var = s2 * (1.0f / N_) - mean * mean;
  var = fmaxf(var, 0.0f);
  const float inv_std = rsqrtf(var + EPS_);
  const float s = gamma[c] * inv_std;

  // softmax over logits s*v (shift-invariant exact form with max subtraction)
  float mx = -INFINITY;
#pragma unroll
  for (int t = 0; t < 6; ++t) mx = fmaxf(mx, s * v[t]);
#pragma unroll
  for (int off = 32; off; off >>= 1) mx = fmaxf(mx, __shfl_xor(mx, off));

  float se = 0.f, swf = 0.f;
#pragma unroll
  for (int t = 0; t < 6; ++t) {
    const float e = expf(s * v[t] - mx);
    se += e;
    swf += e * v[t];
  }
#pragma unroll
  for (int off = 32; off; off >>= 1) {
    se += __shfl_xor(se, off);
    swf += __shfl_xor(swf, off);
  }
  const float M = swf / se;

  if (lane == 0) {
    ws_a[bc] = s;
    ws_u[bc] = fmaf(s, M, beta[c]);
  }
}

// ---------------------------------------------------------------------------
// Kernel B: out[b, 1+i, c] = Kc[b,c] + sum_k F[b,i,k] * WbT[b][k][c]
// where WbT[k][c] = W[c,C+k]*gamma[C+k] - W[c,k]*ws_a[b,k]
//       Kc[c]     = bvec[c] + sum_k ( W[c,k]*ws_u[b,k] + W[c,C+k]*beta[C+k] )
// plus cls row copy out[b,0,:] = x[b,0,:].
// grid = B * (N/ROWS) blocks, 256 threads. ROWS=16.
// ---------------------------------------------------------------------------
#define ROWS_ 16
#define NRT_  (N_ / ROWS_)   // 24

__global__ __launch_bounds__(256) void lnp_gemm_kernel(
    const float* __restrict__ x, const float* __restrict__ gamma,
    const float* __restrict__ beta, const float* __restrict__ W,
    const float* __restrict__ bvec, const float* __restrict__ ws_a,
    const float* __restrict__ ws_u, float* __restrict__ out) {
  __shared__ float WbT[128][129];   // padded: stride 129 -> conflict-free
  __shared__ float Fs[ROWS_][128];
  __shared__ float Kc[128];

  const int blk = blockIdx.x;
  const int b   = blk / NRT_;
  const int rt  = blk % NRT_;
  const int r0  = rt * ROWS_;
  const int t   = threadIdx.x;

  const float* a = ws_a + b * C_;
  const float* u = ws_u + b * C_;

  // Build WbT: reads of W are coalesced over k (contiguous), writes are
  // 2-way-bank at worst due to 129 padding.
  for (int idx = t; idx < 128 * 128; idx += 256) {
    const int k = idx & 127;
    const int c = idx >> 7;
    WbT[k][c] = fmaf(W[c * 256 + 128 + k], gamma[128 + k],
                     -W[c * 256 + k] * a[k]);
  }

  // Stage F tile (coalesced)
  for (int idx = t; idx < ROWS_ * 128; idx += 256) {
    const int r = idx >> 7;
    const int col = idx & 127;
    Fs[r][col] = x[(size_t)b * L_ * C_ + (size_t)(1 + r0 + r) * C_ + col];
  }

  // Per-(b,c) constant
  if (t < 128) {
    const int c = t;
    float acc = bvec[c];
#pragma unroll 4
    for (int k = 0; k < 128; ++k) {
      acc = fmaf(W[c * 256 + k], u[k], acc);
      acc = fmaf(W[c * 256 + 128 + k], beta[128 + k], acc);
    }
    Kc[c] = acc;
  }

  // cls-token passthrough
  if (rt == 0 && t < 128) {
    out[(size_t)b * L_ * C_ + t] = x[(size_t)b * L_ * C_ + t];
  }

  __syncthreads();

  const int c  = t & 127;
  const int rg = t >> 7;   // 0 or 1: which 8-row half this thread owns

  float acc[8];
#pragma unroll
  for (int m = 0; m < 8; ++m) acc[m] = 0.f;

#pragma unroll 4
  for (int k = 0; k < 128; ++k) {
    const float wv = WbT[k][c];
#pragma unroll
    for (int m = 0; m < 8; ++m) {
      acc[m] = fmaf(wv, Fs[rg * 8 + m][k], acc[m]);
    }
  }

#pragma unroll
  for (int m = 0; m < 8; ++m) {
    const int i = r0 + rg * 8 + m;
    out[(size_t)b * L_ * C_ + (size_t)(1 + i) * C_ + c] = acc[m] + Kc[c];
  }
}

extern "C" void kernel_launch(void* const* d_in, const int* in_sizes, int n_in,
                              void* d_out, int out_size, void* d_ws, size_t ws_size,
                              hipStream_t stream) {
  const float* x     = (const float*)d_in[0];
  const float* gamma = (const float*)d_in[1];
  const float* beta  = (const float*)d_in[2];
  const float* W     = (const float*)d_in[3];
  const float* bvec  = (const float*)d_in[4];
  float* out = (float*)d_out;

  float* ws_a = (float*)d_ws;          // B*C = 256 floats
  float* ws_u = ws_a + B_ * C_;        // 256 floats

  lnp_stats_kernel<<<B_ * C_, 64, 0, stream>>>(x, gamma, beta, ws_a, ws_u);
  lnp_gemm_kernel<<<B_ * NRT_, 256, 0, stream>>>(x, gamma, beta, W, bvec,
                                                 ws_a, ws_u, out);
}